// Round 6
// baseline (272.040 us; speedup 1.0000x reference)
//
#include <hip/hip_runtime.h>
#include <math.h>

#define BB 16
#define HH 8
#define SS 512
#define FF 512
#define DD 64
#define RANKK 12
#define KTOP 51
#define ROWS 8

typedef __attribute__((ext_vector_type(8))) short bf16x8;
typedef __attribute__((ext_vector_type(4))) float f32x4;

// ---------- bf16 helpers (explicit RNE, deterministic) ----------
__device__ __forceinline__ unsigned short f2bf(float x){
  unsigned u = __float_as_uint(x);
  return (unsigned short)((u + 0x7FFFu + ((u>>16)&1u)) >> 16);
}
__device__ __forceinline__ float bf2f(unsigned short h){
  return __uint_as_float(((unsigned)h)<<16);
}

// monotonic float->uint order mapping (no NaNs in this problem)
__device__ __forceinline__ unsigned f2ord(float x){
  unsigned u = __float_as_uint(x);
  return (u & 0x80000000u) ? ~u : (u | 0x80000000u);
}

// One wave owns one row of 512 values (8 per lane, f = lane*8+j).
__device__ __forceinline__ void topk_softmax8(float (&a)[8]){
  unsigned key[8];
#pragma unroll
  for (int j=0;j<8;++j) key[j] = f2ord(a[j]);
  unsigned T = 0u;
#pragma unroll
  for (int bit=31; bit>=0; --bit){
    unsigned Tp = T | (1u<<bit);
    int cnt = 0;
#pragma unroll
    for (int j=0;j<8;++j){
      unsigned long long bl = __ballot(key[j] >= Tp);
      cnt += __popcll(bl);
    }
    if (cnt >= KTOP) T = Tp;
  }
  float m = a[0];
#pragma unroll
  for (int j=1;j<8;++j) m = fmaxf(m, a[j]);
#pragma unroll
  for (int off=32; off>=1; off>>=1) m = fmaxf(m, __shfl_xor(m, off));
  float sum = 0.f;
#pragma unroll
  for (int j=0;j<8;++j){
    float e = (key[j] >= T) ? expf(a[j]-m) : 0.f;
    a[j] = e; sum += e;
  }
#pragma unroll
  for (int off=32; off>=1; off>>=1) sum += __shfl_xor(sum, off);
  float inv = 1.f/sum;
#pragma unroll
  for (int j=0;j<8;++j) a[j] *= inv;
}

// Kernel 1: score_ln[b*H+h][f]  (FROZEN — validated bits)
__global__ __launch_bounds__(512) void k_score(const float* __restrict__ values,
    const float* __restrict__ temp, const float* __restrict__ ln_w,
    const float* __restrict__ ln_b, float* __restrict__ score_ln)
{
  const int b = blockIdx.x / HH, h = blockIdx.x % HH;
  const int tid = threadIdx.x, w = tid >> 6, lane = tid & 63;
  __shared__ float s_e[FF];
  __shared__ float ps[8], ps2[8];
  const float* vb = values + ((size_t)b*FF*HH + h)*DD;
  for (int i=0;i<FF/8;++i){
    int f = w*(FF/8) + i;
    float v = vb[(size_t)f*HH*DD + lane];
    float e = v*v;
#pragma unroll
    for (int off=32; off>=1; off>>=1) e += __shfl_xor(e, off);
    if (lane==0) s_e[f] = e * (1.0f/DD);
  }
  __syncthreads();
  float e = s_e[tid];
  float se = e, se2 = e*e;
#pragma unroll
  for (int off=32; off>=1; off>>=1){ se += __shfl_xor(se, off); se2 += __shfl_xor(se2, off); }
  if (lane==0){ ps[w]=se; ps2[w]=se2; }
  __syncthreads();
  float S1=0.f, S2=0.f;
#pragma unroll
  for (int g=0; g<8; ++g){ S1 += ps[g]; S2 += ps2[g]; }
  float meanE = S1 * (1.0f/FF);
  float rms = fmaxf(sqrtf(meanE), 1e-6f);
  float t = temp[h];
  float gain = (t > 20.f) ? t : log1pf(expf(t));
  float c = gain / rms;
  float mu = c * meanE;
  float var = c*c*(S2*(1.0f/FF) - meanE*meanE);
  float inv = rsqrtf(var + 1e-5f);
  score_ln[(size_t)blockIdx.x*FF + tid] = (c*e - mu)*inv*ln_w[tid] + ln_b[tid];
}

// Kernel 2: A_soft[h*S+s][f]  (FROZEN — validated bits)
__global__ __launch_bounds__(512) void k_alpha(const float* __restrict__ alpha,
                                               float* __restrict__ A_soft)
{
  const int w = threadIdx.x >> 6, lane = threadIdx.x & 63;
  const int row = blockIdx.x * ROWS + w;
  const float SCALE = (float)(1.0/sqrt((double)FF));
  const float* ar = alpha + (size_t)row*FF + lane*8;
  float4 v0 = *(const float4*)ar;
  float4 v1 = *(const float4*)(ar+4);
  float a[8] = {v0.x*SCALE, v0.y*SCALE, v0.z*SCALE, v0.w*SCALE,
                v1.x*SCALE, v1.y*SCALE, v1.z*SCALE, v1.w*SCALE};
  topk_softmax8(a);
  float* orow = A_soft + (size_t)row*FF + lane*8;
  *(float4*)orow     = make_float4(a[0],a[1],a[2],a[3]);
  *(float4*)(orow+4) = make_float4(a[4],a[5],a[6],a[7]);
}

// Kernel 2.5: transpose values -> bf16 hi/lo planes  plane[(bloc*H+h)*D+d][f]
__global__ __launch_bounds__(512) void k_prep_t(const float* __restrict__ values,
    unsigned short* __restrict__ hiP, unsigned short* __restrict__ loP, int b0)
{
  const int bloc_h = blockIdx.x;             // bloc*HH + h
  const int b = b0 + bloc_h / HH, h = bloc_h % HH;
  const int tid = threadIdx.x, w = tid >> 6, lane = tid & 63;
  __shared__ float tile[64][65];
  const float* vb = values + ((size_t)b*FF*HH + h)*DD;
  for (int c=0;c<8;++c){
#pragma unroll
    for (int p=0;p<8;++p){
      const int fi = p*8 + w;
      const int f  = c*64 + fi;
      tile[fi][lane] = vb[(size_t)f*HH*DD + lane];
    }
    __syncthreads();
    {
      const int d  = w*8 + (lane>>3);
      const int fj = (lane&7)*8;
      unsigned short hs[8], ls[8];
#pragma unroll
      for (int j=0;j<8;++j){
        float x = tile[fj+j][d];
        hs[j] = f2bf(x);
        ls[j] = f2bf(x - bf2f(hs[j]));
      }
      uint4 H4, L4;
      H4.x=(unsigned)hs[0]|((unsigned)hs[1]<<16); H4.y=(unsigned)hs[2]|((unsigned)hs[3]<<16);
      H4.z=(unsigned)hs[4]|((unsigned)hs[5]<<16); H4.w=(unsigned)hs[6]|((unsigned)hs[7]<<16);
      L4.x=(unsigned)ls[0]|((unsigned)ls[1]<<16); L4.y=(unsigned)ls[2]|((unsigned)ls[3]<<16);
      L4.z=(unsigned)ls[4]|((unsigned)ls[5]<<16); L4.w=(unsigned)ls[6]|((unsigned)ls[7]<<16);
      const size_t base = ((size_t)bloc_h*DD + d)*FF + c*64 + fj;
      *(uint4*)(hiP + base) = H4;
      *(uint4*)(loP + base) = L4;
    }
    __syncthreads();
  }
}

// ---------- phase-1 helper (FROZEN — validated bits) ----------
__device__ __forceinline__ void build_mix_row(int bh, int h, int s, int lane,
    const float* __restrict__ score_ln, const float* __restrict__ gamma,
    const float* __restrict__ U, const float* __restrict__ V,
    const float* __restrict__ A_soft, float4& m0, float4& m1)
{
  const int f0 = lane*8;
  const float* sr = score_ln + (size_t)bh*FF + f0;
  float4 sv0 = *(const float4*)sr;
  float4 sv1 = *(const float4*)(sr+4);
  const float g = gamma[h*SS + s];
  float dl[8] = {sv0.x+g, sv0.y+g, sv0.z+g, sv0.w+g,
                 sv1.x+g, sv1.y+g, sv1.z+g, sv1.w+g};
  const float* Ur = U + ((size_t)h*SS + s)*RANKK;
  const float* Vh = V + (size_t)h*RANKK*FF + f0;
#pragma unroll
  for (int r=0;r<RANKK;++r){
    float u = Ur[r];
    float4 b0 = *(const float4*)(Vh + r*FF);
    float4 b1 = *(const float4*)(Vh + r*FF + 4);
    dl[0] += u*b0.x; dl[1] += u*b0.y; dl[2] += u*b0.z; dl[3] += u*b0.w;
    dl[4] += u*b1.x; dl[5] += u*b1.y; dl[6] += u*b1.z; dl[7] += u*b1.w;
  }
  topk_softmax8(dl);
  const float* arow = A_soft + ((size_t)h*SS + s)*FF + f0;
  float4 a0 = *(const float4*)arow;
  float4 a1 = *(const float4*)(arow+4);
  m0 = make_float4(dl[0]+a0.x, dl[1]+a0.y, dl[2]+a0.z, dl[3]+a0.w);
  m1 = make_float4(dl[4]+a1.x, dl[5]+a1.y, dl[6]+a1.z, dl[7]+a1.w);
}

// ---------- MFMA main: 32 s-rows x 64 d per block; B from hi/lo planes ----------
// bid = h*(16*NB) + sblk*NB + bloc (b innermost) + chunked XCD swizzle:
// per-XCD working set = NB*128KB planes + 1MB A_soft slab < 4MB L2.
template<int NB>
__global__ __launch_bounds__(512, 4) void k_mfma_t(
    const unsigned short* __restrict__ hiP, const unsigned short* __restrict__ loP,
    const float* __restrict__ gamma, const float* __restrict__ U,
    const float* __restrict__ V, const float* __restrict__ score_ln,
    const float* __restrict__ A_soft, float* __restrict__ out, int b0)
{
  __shared__ __align__(16) unsigned char Abuf[65536];  // hi [0,32K), lo [32K,64K)
  const int nwg = HH*16*NB;
  const int bid = (blockIdx.x & 7)*(nwg/8) + (blockIdx.x >> 3); // XCD chunk swizzle
  const int h    = bid / (16*NB);
  const int rr   = bid % (16*NB);
  const int sblk = rr / NB;
  const int bloc = rr % NB;
  const int b    = b0 + bloc;
  const int s0   = sblk*32;
  const int bh   = b*HH + h;
  const int tid = threadIdx.x, w = tid>>6, lane = tid&63;

  // ---- phase 1: wave w builds mix rows sl = w*4 .. w*4+3, stage bf16 hi/lo ----
#pragma unroll
  for (int i=0;i<4;++i){
    const int sl = w*4 + i;
    float4 m0, m1;
    build_mix_row(bh, h, s0+sl, lane, score_ln, gamma, U, V, A_soft, m0, m1);
    float xs[8] = {m0.x,m0.y,m0.z,m0.w,m1.x,m1.y,m1.z,m1.w};
    unsigned short hs[8], ls[8];
#pragma unroll
    for (int j=0;j<8;++j){
      hs[j] = f2bf(xs[j]);
      ls[j] = f2bf(xs[j] - bf2f(hs[j]));
    }
    uint4 H4, L4;
    H4.x = (unsigned)hs[0] | ((unsigned)hs[1]<<16);
    H4.y = (unsigned)hs[2] | ((unsigned)hs[3]<<16);
    H4.z = (unsigned)hs[4] | ((unsigned)hs[5]<<16);
    H4.w = (unsigned)hs[6] | ((unsigned)hs[7]<<16);
    L4.x = (unsigned)ls[0] | ((unsigned)ls[1]<<16);
    L4.y = (unsigned)ls[2] | ((unsigned)ls[3]<<16);
    L4.z = (unsigned)ls[4] | ((unsigned)ls[5]<<16);
    L4.w = (unsigned)ls[6] | ((unsigned)ls[7]<<16);
    const unsigned byt = (unsigned)(sl*1024 + lane*16) ^ (unsigned)((sl&15)<<4);
    *(uint4*)(Abuf + byt)          = H4;
    *(uint4*)(Abuf + 32768 + byt)  = L4;
  }
  __syncthreads();

  // ---- phase 2: wave (stile,ntile) computes 16s x 16d, K=512 ----
  const int stile = w>>2, ntile = w&3;
  const int srow  = stile*16 + (lane&15);
  const unsigned sw = (unsigned)((lane&15)<<4);
  const unsigned a0off = (unsigned)(srow*1024 + ((lane>>4)*16));
  const int d    = ntile*16 + (lane&15);
  const int frow = (lane>>4)*8;

  f32x4 acc0 = {0.f,0.f,0.f,0.f};
  f32x4 acc1 = {0.f,0.f,0.f,0.f};

  const size_t pb = ((size_t)(bloc*HH + h)*DD + d)*FF + frow;
  const unsigned short* hp = hiP + pb;
  const unsigned short* lp = loP + pb;

#pragma unroll
  for (int t=0;t<16;++t){
    const unsigned ax = (a0off + (unsigned)(t*64)) ^ sw;
    bf16x8 ah = *(const bf16x8*)(Abuf + ax);
    bf16x8 al = *(const bf16x8*)(Abuf + 32768 + ax);
    bf16x8 bhv = *(const bf16x8*)(hp + t*32);
    bf16x8 blv = *(const bf16x8*)(lp + t*32);
    acc0 = __builtin_amdgcn_mfma_f32_16x16x32_bf16(ah, bhv, acc0, 0, 0, 0);
    acc1 = __builtin_amdgcn_mfma_f32_16x16x32_bf16(al, bhv, acc1, 0, 0, 0);
    acc1 = __builtin_amdgcn_mfma_f32_16x16x32_bf16(ah, blv, acc1, 0, 0, 0);
  }

  // ---- epilogue: C/D map col=lane&15 (n=d), row=(lane>>4)*4+reg (m=s) ----
  const int m0r = stile*16 + (lane>>4)*4;
#pragma unroll
  for (int r=0;r<4;++r){
    const int s = s0 + m0r + r;
    out[(((size_t)b*SS + s)*HH + h)*DD + d] = acc0[r] + acc1[r];
  }
}

// ---------- fallback: r1 LDS-broadcast kernel (tiny-ws safety) ----------
__global__ __launch_bounds__(512) void k_main_lds(const float* __restrict__ values,
    const float* __restrict__ alpha, const float* __restrict__ gamma,
    const float* __restrict__ U, const float* __restrict__ V,
    const float* __restrict__ score_ln, float* __restrict__ out)
{
  const int nwg = BB*HH*(SS/ROWS);
  const int bid = (blockIdx.x & 7)*(nwg/8) + (blockIdx.x >> 3);
  const int blocksPerBH = SS / ROWS;
  const int bh = bid / blocksPerBH;
  const int s0 = (bid % blocksPerBH) * ROWS;
  const int b = bh / HH, h = bh % HH;
  const int tid = threadIdx.x, w = tid >> 6, lane = tid & 63;
  __shared__ float smix[ROWS][FF];

  {
    const int s = s0 + w;
    const int f0 = lane*8;
    const float* sr = score_ln + (size_t)bh*FF + f0;
    float4 sv0 = *(const float4*)sr;
    float4 sv1 = *(const float4*)(sr+4);
    const float g = gamma[h*SS + s];
    float dl[8] = {sv0.x+g, sv0.y+g, sv0.z+g, sv0.w+g,
                   sv1.x+g, sv1.y+g, sv1.z+g, sv1.w+g};
    const float* Ur = U + ((size_t)h*SS + s)*RANKK;
    const float* Vh = V + (size_t)h*RANKK*FF + f0;
#pragma unroll
    for (int r=0;r<RANKK;++r){
      float u = Ur[r];
      float4 b0 = *(const float4*)(Vh + r*FF);
      float4 b1 = *(const float4*)(Vh + r*FF + 4);
      dl[0] += u*b0.x; dl[1] += u*b0.y; dl[2] += u*b0.z; dl[3] += u*b0.w;
      dl[4] += u*b1.x; dl[5] += u*b1.y; dl[6] += u*b1.z; dl[7] += u*b1.w;
    }
    topk_softmax8(dl);
    const float SCALE = (float)(1.0/sqrt((double)FF));
    const float* arow = alpha + ((size_t)h*SS + s)*FF + f0;
    float4 a0 = *(const float4*)arow;
    float4 a1 = *(const float4*)(arow+4);
    float ap[8] = {a0.x*SCALE, a0.y*SCALE, a0.z*SCALE, a0.w*SCALE,
                   a1.x*SCALE, a1.y*SCALE, a1.z*SCALE, a1.w*SCALE};
    topk_softmax8(ap);
    float4 m0 = make_float4(dl[0]+ap[0], dl[1]+ap[1], dl[2]+ap[2], dl[3]+ap[3]);
    float4 m1 = make_float4(dl[4]+ap[4], dl[5]+ap[5], dl[6]+ap[6], dl[7]+ap[7]);
    *(float4*)&smix[w][f0]   = m0;
    *(float4*)&smix[w][f0+4] = m1;
  }
  __syncthreads();

  float acc[ROWS] = {0,0,0,0,0,0,0,0};
  {
    const float* vp = values + (size_t)b*FF*HH*DD + (size_t)h*DD + lane;
#pragma unroll
    for (int i=0;i<16;++i){
      const int f0 = w*64 + i*4;
      float x0 = vp[(size_t)(f0+0)*HH*DD];
      float x1 = vp[(size_t)(f0+1)*HH*DD];
      float x2 = vp[(size_t)(f0+2)*HH*DD];
      float x3 = vp[(size_t)(f0+3)*HH*DD];
#pragma unroll
      for (int r=0;r<ROWS;++r){
        float4 m = *(const float4*)&smix[r][f0];
        acc[r] += m.x*x0 + m.y*x1 + m.z*x2 + m.w*x3;
      }
    }
  }
  __syncthreads();

  float* red = &smix[0][0];
#pragma unroll
  for (int r=0;r<ROWS;++r) red[(w*ROWS + r)*64 + lane] = acc[r];
  __syncthreads();
  {
    const int r = w, dd = lane;
    float sum = 0.f;
#pragma unroll
    for (int g=0; g<8; ++g) sum += red[(g*ROWS + r)*64 + dd];
    out[(((size_t)b*SS + s0 + r)*HH + h)*DD + dd] = sum;
  }
}

extern "C" void kernel_launch(void* const* d_in, const int* in_sizes, int n_in,
                              void* d_out, int out_size, void* d_ws, size_t ws_size,
                              hipStream_t stream) {
  const float* values = (const float*)d_in[0];
  const float* alpha  = (const float*)d_in[1];
  const float* temp   = (const float*)d_in[2];
  const float* gamma  = (const float*)d_in[3];
  const float* U      = (const float*)d_in[4];
  const float* V      = (const float*)d_in[5];
  const float* ln_w   = (const float*)d_in[6];
  const float* ln_b   = (const float*)d_in[7];
  float* out = (float*)d_out;
  float* ws  = (float*)d_ws;

  const size_t scoreN = (size_t)BB*HH*FF;             // 65,536 floats
  const size_t alphaN = (size_t)HH*SS*FF;             // 2,097,152 floats
  const size_t planeFull = (size_t)BB*HH*DD*FF;       // 4,194,304 ushorts/plane
  const size_t planeHalf = planeFull/2;

  float* score_ln = ws;
  float* A_soft   = ws + scoreN;
  unsigned short* hiP = (unsigned short*)(ws + scoreN + alphaN);

  const size_t baseB    = (scoreN + alphaN)*sizeof(float);             // 8.65 MB
  const size_t needFull = baseB + 2*planeFull*sizeof(unsigned short);  // 25.4 MB
  const size_t needHalf = baseB + 2*planeHalf*sizeof(unsigned short);  // 17.0 MB (r2-proven)

  hipLaunchKernelGGL(k_score, dim3(BB*HH), dim3(512), 0, stream,
                     values, temp, ln_w, ln_b, score_ln);
  if (ws_size >= needFull){
    unsigned short* loP = hiP + planeFull;
    hipLaunchKernelGGL(k_alpha, dim3(HH*SS/ROWS), dim3(512), 0, stream, alpha, A_soft);
    hipLaunchKernelGGL(k_prep_t, dim3(BB*HH), dim3(512), 0, stream, values, hiP, loP, 0);
    hipLaunchKernelGGL((k_mfma_t<BB>), dim3(HH*16*BB), dim3(512), 0, stream,
                       hiP, loP, gamma, U, V, score_ln, A_soft, out, 0);
  } else if (ws_size >= needHalf){
    unsigned short* loP = hiP + planeHalf;
    hipLaunchKernelGGL(k_alpha, dim3(HH*SS/ROWS), dim3(512), 0, stream, alpha, A_soft);
    for (int c=0;c<2;++c){
      hipLaunchKernelGGL(k_prep_t, dim3((BB/2)*HH), dim3(512), 0, stream,
                         values, hiP, loP, c*(BB/2));
      hipLaunchKernelGGL((k_mfma_t<BB/2>), dim3(HH*16*(BB/2)), dim3(512), 0, stream,
                         hiP, loP, gamma, U, V, score_ln, A_soft, out, c*(BB/2));
    }
  } else {
    hipLaunchKernelGGL(k_main_lds, dim3(BB*HH*(SS/ROWS)), dim3(512), 0, stream,
                       values, alpha, gamma, U, V, score_ln, out);
  }
}

// Round 7
// 181.941 us; speedup vs baseline: 1.4952x; 1.4952x over previous
//
#include <hip/hip_runtime.h>
#include <math.h>

#define BB 16
#define HH 8
#define SS 512
#define FF 512
#define DD 64
#define RANKK 12
#define KTOP 51
#define ROWS 8

typedef __attribute__((ext_vector_type(8))) short bf16x8;
typedef __attribute__((ext_vector_type(4))) float f32x4;

// ---------- bf16 helpers (explicit RNE, deterministic) ----------
__device__ __forceinline__ unsigned short f2bf(float x){
  unsigned u = __float_as_uint(x);
  return (unsigned short)((u + 0x7FFFu + ((u>>16)&1u)) >> 16);
}
__device__ __forceinline__ float bf2f(unsigned short h){
  return __uint_as_float(((unsigned)h)<<16);
}

// monotonic float->uint order mapping (no NaNs in this problem)
__device__ __forceinline__ unsigned f2ord(float x){
  unsigned u = __float_as_uint(x);
  return (u & 0x80000000u) ? ~u : (u | 0x80000000u);
}

// One wave owns one row of 512 values (8 per lane, f = lane*8+j).
// Early exit when cnt==KTOP is EXACT: |{key>=Tp}|==KTOP implies
// mask(key>=Tp) == mask(key>=kth) (kth = min of that set), so the
// kept set — and therefore all downstream fp bits — are identical.
__device__ __forceinline__ void topk_softmax8(float (&a)[8]){
  unsigned key[8];
#pragma unroll
  for (int j=0;j<8;++j) key[j] = f2ord(a[j]);
  unsigned T = 0u;
#pragma unroll
  for (int bit=31; bit>=0; --bit){
    unsigned Tp = T | (1u<<bit);
    int cnt = 0;
#pragma unroll
    for (int j=0;j<8;++j){
      unsigned long long bl = __ballot(key[j] >= Tp);
      cnt += __popcll(bl);
    }
    if (cnt >= KTOP) T = Tp;
    if (cnt == KTOP) break;            // wave-uniform exact early exit
  }
  float m = a[0];
#pragma unroll
  for (int j=1;j<8;++j) m = fmaxf(m, a[j]);
#pragma unroll
  for (int off=32; off>=1; off>>=1) m = fmaxf(m, __shfl_xor(m, off));
  float sum = 0.f;
#pragma unroll
  for (int j=0;j<8;++j){
    float e = (key[j] >= T) ? expf(a[j]-m) : 0.f;
    a[j] = e; sum += e;
  }
#pragma unroll
  for (int off=32; off>=1; off>>=1) sum += __shfl_xor(sum, off);
  float inv = 1.f/sum;
#pragma unroll
  for (int j=0;j<8;++j) a[j] *= inv;
}

// Kernel 1: score_ln[b*H+h][f]  (FROZEN — validated bits)
__global__ __launch_bounds__(512) void k_score(const float* __restrict__ values,
    const float* __restrict__ temp, const float* __restrict__ ln_w,
    const float* __restrict__ ln_b, float* __restrict__ score_ln)
{
  const int b = blockIdx.x / HH, h = blockIdx.x % HH;
  const int tid = threadIdx.x, w = tid >> 6, lane = tid & 63;
  __shared__ float s_e[FF];
  __shared__ float ps[8], ps2[8];
  const float* vb = values + ((size_t)b*FF*HH + h)*DD;
  for (int i=0;i<FF/8;++i){
    int f = w*(FF/8) + i;
    float v = vb[(size_t)f*HH*DD + lane];
    float e = v*v;
#pragma unroll
    for (int off=32; off>=1; off>>=1) e += __shfl_xor(e, off);
    if (lane==0) s_e[f] = e * (1.0f/DD);
  }
  __syncthreads();
  float e = s_e[tid];
  float se = e, se2 = e*e;
#pragma unroll
  for (int off=32; off>=1; off>>=1){ se += __shfl_xor(se, off); se2 += __shfl_xor(se2, off); }
  if (lane==0){ ps[w]=se; ps2[w]=se2; }
  __syncthreads();
  float S1=0.f, S2=0.f;
#pragma unroll
  for (int g=0; g<8; ++g){ S1 += ps[g]; S2 += ps2[g]; }
  float meanE = S1 * (1.0f/FF);
  float rms = fmaxf(sqrtf(meanE), 1e-6f);
  float t = temp[h];
  float gain = (t > 20.f) ? t : log1pf(expf(t));
  float c = gain / rms;
  float mu = c * meanE;
  float var = c*c*(S2*(1.0f/FF) - meanE*meanE);
  float inv = rsqrtf(var + 1e-5f);
  score_ln[(size_t)blockIdx.x*FF + tid] = (c*e - mu)*inv*ln_w[tid] + ln_b[tid];
}

// Kernel 2: A_soft[h*S+s][f]  (FROZEN — validated bits)
__global__ __launch_bounds__(512) void k_alpha(const float* __restrict__ alpha,
                                               float* __restrict__ A_soft)
{
  const int w = threadIdx.x >> 6, lane = threadIdx.x & 63;
  const int row = blockIdx.x * ROWS + w;
  const float SCALE = (float)(1.0/sqrt((double)FF));
  const float* ar = alpha + (size_t)row*FF + lane*8;
  float4 v0 = *(const float4*)ar;
  float4 v1 = *(const float4*)(ar+4);
  float a[8] = {v0.x*SCALE, v0.y*SCALE, v0.z*SCALE, v0.w*SCALE,
                v1.x*SCALE, v1.y*SCALE, v1.z*SCALE, v1.w*SCALE};
  topk_softmax8(a);
  float* orow = A_soft + (size_t)row*FF + lane*8;
  *(float4*)orow     = make_float4(a[0],a[1],a[2],a[3]);
  *(float4*)(orow+4) = make_float4(a[4],a[5],a[6],a[7]);
}

// Kernel 2.5: transpose values -> bf16 hi/lo planes  plane[(bloc*H+h)*D+d][f]
__global__ __launch_bounds__(512) void k_prep_t(const float* __restrict__ values,
    unsigned short* __restrict__ hiP, unsigned short* __restrict__ loP, int b0)
{
  const int bloc_h = blockIdx.x;             // bloc*HH + h
  const int b = b0 + bloc_h / HH, h = bloc_h % HH;
  const int tid = threadIdx.x, w = tid >> 6, lane = tid & 63;
  __shared__ float tile[64][65];
  const float* vb = values + ((size_t)b*FF*HH + h)*DD;
  for (int c=0;c<8;++c){
#pragma unroll
    for (int p=0;p<8;++p){
      const int fi = p*8 + w;
      const int f  = c*64 + fi;
      tile[fi][lane] = vb[(size_t)f*HH*DD + lane];
    }
    __syncthreads();
    {
      const int d  = w*8 + (lane>>3);
      const int fj = (lane&7)*8;
      unsigned short hs[8], ls[8];
#pragma unroll
      for (int j=0;j<8;++j){
        float x = tile[fj+j][d];
        hs[j] = f2bf(x);
        ls[j] = f2bf(x - bf2f(hs[j]));
      }
      uint4 H4, L4;
      H4.x=(unsigned)hs[0]|((unsigned)hs[1]<<16); H4.y=(unsigned)hs[2]|((unsigned)hs[3]<<16);
      H4.z=(unsigned)hs[4]|((unsigned)hs[5]<<16); H4.w=(unsigned)hs[6]|((unsigned)hs[7]<<16);
      L4.x=(unsigned)ls[0]|((unsigned)ls[1]<<16); L4.y=(unsigned)ls[2]|((unsigned)ls[3]<<16);
      L4.z=(unsigned)ls[4]|((unsigned)ls[5]<<16); L4.w=(unsigned)ls[6]|((unsigned)ls[7]<<16);
      const size_t base = ((size_t)bloc_h*DD + d)*FF + c*64 + fj;
      *(uint4*)(hiP + base) = H4;
      *(uint4*)(loP + base) = L4;
    }
    __syncthreads();
  }
}

// ---------- phase-1 helper (FROZEN — validated bits) ----------
__device__ __forceinline__ void build_mix_row(int bh, int h, int s, int lane,
    const float* __restrict__ score_ln, const float* __restrict__ gamma,
    const float* __restrict__ U, const float* __restrict__ V,
    const float* __restrict__ A_soft, float4& m0, float4& m1)
{
  const int f0 = lane*8;
  const float* sr = score_ln + (size_t)bh*FF + f0;
  float4 sv0 = *(const float4*)sr;
  float4 sv1 = *(const float4*)(sr+4);
  const float g = gamma[h*SS + s];
  float dl[8] = {sv0.x+g, sv0.y+g, sv0.z+g, sv0.w+g,
                 sv1.x+g, sv1.y+g, sv1.z+g, sv1.w+g};
  const float* Ur = U + ((size_t)h*SS + s)*RANKK;
  const float* Vh = V + (size_t)h*RANKK*FF + f0;
#pragma unroll
  for (int r=0;r<RANKK;++r){
    float u = Ur[r];
    float4 b0 = *(const float4*)(Vh + r*FF);
    float4 b1 = *(const float4*)(Vh + r*FF + 4);
    dl[0] += u*b0.x; dl[1] += u*b0.y; dl[2] += u*b0.z; dl[3] += u*b0.w;
    dl[4] += u*b1.x; dl[5] += u*b1.y; dl[6] += u*b1.z; dl[7] += u*b1.w;
  }
  topk_softmax8(dl);
  const float* arow = A_soft + ((size_t)h*SS + s)*FF + f0;
  float4 a0 = *(const float4*)arow;
  float4 a1 = *(const float4*)(arow+4);
  m0 = make_float4(dl[0]+a0.x, dl[1]+a0.y, dl[2]+a0.z, dl[3]+a0.w);
  m1 = make_float4(dl[4]+a1.x, dl[5]+a1.y, dl[6]+a1.z, dl[7]+a1.w);
}

__device__ __forceinline__ void gload16(const void* g, void* l){
  __builtin_amdgcn_global_load_lds(
      (const __attribute__((address_space(1))) unsigned int*)g,
      (__attribute__((address_space(3))) unsigned int*)l, 16, 0, 0);
}

#define VMCNT1 asm volatile("s_waitcnt vmcnt(1)" ::: "memory")
#define VMCNT0 asm volatile("s_waitcnt vmcnt(0)" ::: "memory")
#define LGKM0  asm volatile("s_waitcnt lgkmcnt(0)" ::: "memory")
#define MEMFENCE asm volatile("" ::: "memory")

// ---------- MFMA main: 32 s-rows x 64 d per block; B async-staged in LDS ----
// bid = (h*NB + bloc)*16 + sblk  (sblk innermost: 16 consecutive blocks share
// one 128KB plane-pair). B chunk per K-step t: [64 d][hi 64B | lo 64B] = 8 KB,
// seg-swizzled s8' = s8 ^ (d&7); linear LDS dest (global_load_lds) with
// pre-swizzled per-lane GLOBAL source; swizzled read side. Double-buffered,
// counted vmcnt(1), stage(0) issued at kernel top to hide under phase-1 VALU.
template<int NB>
__global__ __launch_bounds__(512, 4) void k_mfma_t(
    const unsigned short* __restrict__ hiP, const unsigned short* __restrict__ loP,
    const float* __restrict__ gamma, const float* __restrict__ U,
    const float* __restrict__ V, const float* __restrict__ score_ln,
    const float* __restrict__ A_soft, float* __restrict__ out, int b0)
{
  __shared__ __align__(16) unsigned char Abuf[65536];   // A hi [0,32K), lo [32K,64K)
  __shared__ __align__(16) unsigned char Bbuf[2][8192]; // B chunk dbuf
  const int nwg = HH*NB*16;
  const int bid = (blockIdx.x & 7)*(nwg/8) + (blockIdx.x >> 3); // XCD chunk swizzle
  const int grp  = bid >> 4;           // h*NB + bloc
  const int sblk = bid & 15;
  const int h    = grp / NB;
  const int bloc = grp % NB;
  const int b    = b0 + bloc;
  const int s0   = sblk*32;
  const int bh   = b*HH + h;
  const int tid = threadIdx.x, w = tid>>6, lane = tid&63;

  // ---- staging source decode (rule 21: linear LDS dest, pre-swizzled src) ----
  const size_t pbBase = (size_t)(bloc*HH + h)*DD*FF;
  const int dw  = tid >> 3;            // d row 0..63
  const int s8p = tid & 7;             // swizzled 16B slot in 128B row
  const int s8  = s8p ^ (dw & 7);      // unswizzled slot: plane*4 + seg
  const unsigned short* sp = ((s8 & 4) ? loP : hiP)
                             + pbBase + (size_t)dw*FF + (size_t)(s8 & 3)*8;
  // stage(0) NOW — latency hides under phase-1 top-k
  gload16(sp, &Bbuf[0][(unsigned)w<<10]);

  // ---- phase 1: wave w builds mix rows sl = w*4 .. w*4+3, stage bf16 hi/lo ----
#pragma unroll
  for (int i=0;i<4;++i){
    const int sl = w*4 + i;
    float4 m0, m1;
    build_mix_row(bh, h, s0+sl, lane, score_ln, gamma, U, V, A_soft, m0, m1);
    float xs[8] = {m0.x,m0.y,m0.z,m0.w,m1.x,m1.y,m1.z,m1.w};
    unsigned short hs[8], ls[8];
#pragma unroll
    for (int j=0;j<8;++j){
      hs[j] = f2bf(xs[j]);
      ls[j] = f2bf(xs[j] - bf2f(hs[j]));
    }
    uint4 H4, L4;
    H4.x = (unsigned)hs[0] | ((unsigned)hs[1]<<16);
    H4.y = (unsigned)hs[2] | ((unsigned)hs[3]<<16);
    H4.z = (unsigned)hs[4] | ((unsigned)hs[5]<<16);
    H4.w = (unsigned)hs[6] | ((unsigned)hs[7]<<16);
    L4.x = (unsigned)ls[0] | ((unsigned)ls[1]<<16);
    L4.y = (unsigned)ls[2] | ((unsigned)ls[3]<<16);
    L4.z = (unsigned)ls[4] | ((unsigned)ls[5]<<16);
    L4.w = (unsigned)ls[6] | ((unsigned)ls[7]<<16);
    const unsigned byt = (unsigned)(sl*1024 + lane*16) ^ (unsigned)((sl&15)<<4);
    *(uint4*)(Abuf + byt)          = H4;
    *(uint4*)(Abuf + 32768 + byt)  = L4;
  }
  __syncthreads();   // drains everything incl. stage(0)

  // ---- phase 2: wave (stile,ntile) computes 16s x 16d, K=512 ----
  const int stile = w>>2, ntile = w&3;
  const int srow  = stile*16 + (lane&15);
  const unsigned sw = (unsigned)((lane&15)<<4);
  const unsigned a0off = (unsigned)(srow*1024 + ((lane>>4)*16));
  const int d    = ntile*16 + (lane&15);
  const int sgr  = lane>>4;
  const unsigned offH = (unsigned)(d*128 + ((sgr    ) ^ (d&7))*16);
  const unsigned offL = (unsigned)(d*128 + ((sgr + 4) ^ (d&7))*16);

  f32x4 acc0 = {0.f,0.f,0.f,0.f};
  f32x4 acc1 = {0.f,0.f,0.f,0.f};

#pragma unroll
  for (int t=0;t<16;++t){
    if (t < 15){
      gload16(sp + (size_t)(t+1)*32, &Bbuf[(t+1)&1][(unsigned)w<<10]);
      VMCNT1;                 // stage(t) landed (own wave); barrier -> all waves
    } else {
      VMCNT0;
    }
    __builtin_amdgcn_s_barrier();
    MEMFENCE;
    const unsigned ax = (a0off + (unsigned)(t*64)) ^ sw;
    bf16x8 ah = *(const bf16x8*)(Abuf + ax);
    bf16x8 al = *(const bf16x8*)(Abuf + 32768 + ax);
    const unsigned char* bb = Bbuf[t&1];
    bf16x8 bhv = *(const bf16x8*)(bb + offH);
    bf16x8 blv = *(const bf16x8*)(bb + offL);
    acc0 = __builtin_amdgcn_mfma_f32_16x16x32_bf16(ah, bhv, acc0, 0, 0, 0);
    acc1 = __builtin_amdgcn_mfma_f32_16x16x32_bf16(al, bhv, acc1, 0, 0, 0);
    acc1 = __builtin_amdgcn_mfma_f32_16x16x32_bf16(ah, blv, acc1, 0, 0, 0);
    if (t < 15){
      LGKM0;                  // my ds_reads of Bbuf[t&1] retired before anyone
      __builtin_amdgcn_s_barrier();   // stages into it at iter t+1
      MEMFENCE;
    }
  }

  // ---- epilogue: C/D map col=lane&15 (n=d), row=(lane>>4)*4+reg (m=s) ----
  const int m0r = stile*16 + (lane>>4)*4;
#pragma unroll
  for (int r=0;r<4;++r){
    const int s = s0 + m0r + r;
    __builtin_nontemporal_store(acc0[r] + acc1[r],
        &out[(((size_t)b*SS + s)*HH + h)*DD + d]);
  }
}

// ---------- fallback: r1 LDS-broadcast kernel (tiny-ws safety) ----------
__global__ __launch_bounds__(512) void k_main_lds(const float* __restrict__ values,
    const float* __restrict__ alpha, const float* __restrict__ gamma,
    const float* __restrict__ U, const float* __restrict__ V,
    const float* __restrict__ score_ln, float* __restrict__ out)
{
  const int nwg = BB*HH*(SS/ROWS);
  const int bid = (blockIdx.x & 7)*(nwg/8) + (blockIdx.x >> 3);
  const int blocksPerBH = SS / ROWS;
  const int bh = bid / blocksPerBH;
  const int s0 = (bid % blocksPerBH) * ROWS;
  const int b = bh / HH, h = bh % HH;
  const int tid = threadIdx.x, w = tid >> 6, lane = tid & 63;
  __shared__ float smix[ROWS][FF];

  {
    const int s = s0 + w;
    const int f0 = lane*8;
    const float* sr = score_ln + (size_t)bh*FF + f0;
    float4 sv0 = *(const float4*)sr;
    float4 sv1 = *(const float4*)(sr+4);
    const float g = gamma[h*SS + s];
    float dl[8] = {sv0.x+g, sv0.y+g, sv0.z+g, sv0.w+g,
                   sv1.x+g, sv1.y+g, sv1.z+g, sv1.w+g};
    const float* Ur = U + ((size_t)h*SS + s)*RANKK;
    const float* Vh = V + (size_t)h*RANKK*FF + f0;
#pragma unroll
    for (int r=0;r<RANKK;++r){
      float u = Ur[r];
      float4 b0 = *(const float4*)(Vh + r*FF);
      float4 b1 = *(const float4*)(Vh + r*FF + 4);
      dl[0] += u*b0.x; dl[1] += u*b0.y; dl[2] += u*b0.z; dl[3] += u*b0.w;
      dl[4] += u*b1.x; dl[5] += u*b1.y; dl[6] += u*b1.z; dl[7] += u*b1.w;
    }
    topk_softmax8(dl);
    const float SCALE = (float)(1.0/sqrt((double)FF));
    const float* arow = alpha + ((size_t)h*SS + s)*FF + f0;
    float4 a0 = *(const float4*)arow;
    float4 a1 = *(const float4*)(arow+4);
    float ap[8] = {a0.x*SCALE, a0.y*SCALE, a0.z*SCALE, a0.w*SCALE,
                   a1.x*SCALE, a1.y*SCALE, a1.z*SCALE, a1.w*SCALE};
    topk_softmax8(ap);
    float4 m0 = make_float4(dl[0]+ap[0], dl[1]+ap[1], dl[2]+ap[2], dl[3]+ap[3]);
    float4 m1 = make_float4(dl[4]+ap[4], dl[5]+ap[5], dl[6]+ap[6], dl[7]+ap[7]);
    *(float4*)&smix[w][f0]   = m0;
    *(float4*)&smix[w][f0+4] = m1;
  }
  __syncthreads();

  float acc[ROWS] = {0,0,0,0,0,0,0,0};
  {
    const float* vp = values + (size_t)b*FF*HH*DD + (size_t)h*DD + lane;
#pragma unroll
    for (int i=0;i<16;++i){
      const int f0 = w*64 + i*4;
      float x0 = vp[(size_t)(f0+0)*HH*DD];
      float x1 = vp[(size_t)(f0+1)*HH*DD];
      float x2 = vp[(size_t)(f0+2)*HH*DD];
      float x3 = vp[(size_t)(f0+3)*HH*DD];
#pragma unroll
      for (int r=0;r<ROWS;++r){
        float4 m = *(const float4*)&smix[r][f0];
        acc[r] += m.x*x0 + m.y*x1 + m.z*x2 + m.w*x3;
      }
    }
  }
  __syncthreads();

  float* red = &smix[0][0];
#pragma unroll
  for (int r=0;r<ROWS;++r) red[(w*ROWS + r)*64 + lane] = acc[r];
  __syncthreads();
  {
    const int r = w, dd = lane;
    float sum = 0.f;
#pragma unroll
    for (int g=0; g<8; ++g) sum += red[(g*ROWS + r)*64 + dd];
    out[(((size_t)b*SS + s0 + r)*HH + h)*DD + dd] = sum;
  }
}

extern "C" void kernel_launch(void* const* d_in, const int* in_sizes, int n_in,
                              void* d_out, int out_size, void* d_ws, size_t ws_size,
                              hipStream_t stream) {
  const float* values = (const float*)d_in[0];
  const float* alpha  = (const float*)d_in[1];
  const float* temp   = (const float*)d_in[2];
  const float* gamma  = (const float*)d_in[3];
  const float* U      = (const float*)d_in[4];
  const float* V      = (const float*)d_in[5];
  const float* ln_w   = (const float*)d_in[6];
  const float* ln_b   = (const float*)d_in[7];
  float* out = (float*)d_out;
  float* ws  = (float*)d_ws;

  const size_t scoreN = (size_t)BB*HH*FF;             // 65,536 floats
  const size_t alphaN = (size_t)HH*SS*FF;             // 2,097,152 floats
  const size_t planeFull = (size_t)BB*HH*DD*FF;       // 4,194,304 ushorts/plane
  const size_t planeHalf = planeFull/2;

  float* score_ln = ws;
  float* A_soft   = ws + scoreN;
  unsigned short* hiP = (unsigned short*)(ws + scoreN + alphaN);

  const size_t baseB    = (scoreN + alphaN)*sizeof(float);             // 8.65 MB
  const size_t needFull = baseB + 2*planeFull*sizeof(unsigned short);  // 25.4 MB
  const size_t needHalf = baseB + 2*planeHalf*sizeof(unsigned short);  // 17.0 MB (r2-proven)

  hipLaunchKernelGGL(k_score, dim3(BB*HH), dim3(512), 0, stream,
                     values, temp, ln_w, ln_b, score_ln);
  if (ws_size >= needFull){
    unsigned short* loP = hiP + planeFull;
    hipLaunchKernelGGL(k_alpha, dim3(HH*SS/ROWS), dim3(512), 0, stream, alpha, A_soft);
    hipLaunchKernelGGL(k_prep_t, dim3(BB*HH), dim3(512), 0, stream, values, hiP, loP, 0);
    hipLaunchKernelGGL((k_mfma_t<BB>), dim3(HH*16*BB), dim3(512), 0, stream,
                       hiP, loP, gamma, U, V, score_ln, A_soft, out, 0);
  } else if (ws_size >= needHalf){
    unsigned short* loP = hiP + planeHalf;
    hipLaunchKernelGGL(k_alpha, dim3(HH*SS/ROWS), dim3(512), 0, stream, alpha, A_soft);
    for (int c=0;c<2;++c){
      hipLaunchKernelGGL(k_prep_t, dim3((BB/2)*HH), dim3(512), 0, stream,
                         values, hiP, loP, c*(BB/2));
      hipLaunchKernelGGL((k_mfma_t<BB/2>), dim3(HH*16*(BB/2)), dim3(512), 0, stream,
                         hiP, loP, gamma, U, V, score_ln, A_soft, out, c*(BB/2));
    }
  } else {
    hipLaunchKernelGGL(k_main_lds, dim3(BB*HH*(SS/ROWS)), dim3(512), 0, stream,
                       values, alpha, gamma, U, V, score_ln, out);
  }
}

// Round 8
// 173.521 us; speedup vs baseline: 1.5678x; 1.0485x over previous
//
#include <hip/hip_runtime.h>
#include <math.h>

#define BB 16
#define HH 8
#define SS 512
#define FF 512
#define DD 64
#define RANKK 12
#define KTOP 51
#define ROWS 8

typedef __attribute__((ext_vector_type(8))) short bf16x8;
typedef __attribute__((ext_vector_type(4))) float f32x4;

// ---------- bf16 helpers (explicit RNE, deterministic) ----------
__device__ __forceinline__ unsigned short f2bf(float x){
  unsigned u = __float_as_uint(x);
  return (unsigned short)((u + 0x7FFFu + ((u>>16)&1u)) >> 16);
}
__device__ __forceinline__ float bf2f(unsigned short h){
  return __uint_as_float(((unsigned)h)<<16);
}

// monotonic float->uint order mapping (no NaNs in this problem)
__device__ __forceinline__ unsigned f2ord(float x){
  unsigned u = __float_as_uint(x);
  return (u & 0x80000000u) ? ~u : (u | 0x80000000u);
}

// One wave owns one row of 512 values (8 per lane, f = lane*8+j).
// Early exit when cnt==KTOP is EXACT (kept set identical).  (FROZEN)
__device__ __forceinline__ void topk_softmax8(float (&a)[8]){
  unsigned key[8];
#pragma unroll
  for (int j=0;j<8;++j) key[j] = f2ord(a[j]);
  unsigned T = 0u;
#pragma unroll
  for (int bit=31; bit>=0; --bit){
    unsigned Tp = T | (1u<<bit);
    int cnt = 0;
#pragma unroll
    for (int j=0;j<8;++j){
      unsigned long long bl = __ballot(key[j] >= Tp);
      cnt += __popcll(bl);
    }
    if (cnt >= KTOP) T = Tp;
    if (cnt == KTOP) break;            // wave-uniform exact early exit
  }
  float m = a[0];
#pragma unroll
  for (int j=1;j<8;++j) m = fmaxf(m, a[j]);
#pragma unroll
  for (int off=32; off>=1; off>>=1) m = fmaxf(m, __shfl_xor(m, off));
  float sum = 0.f;
#pragma unroll
  for (int j=0;j<8;++j){
    float e = (key[j] >= T) ? expf(a[j]-m) : 0.f;
    a[j] = e; sum += e;
  }
#pragma unroll
  for (int off=32; off>=1; off>>=1) sum += __shfl_xor(sum, off);
  float inv = 1.f/sum;
#pragma unroll
  for (int j=0;j<8;++j) a[j] *= inv;
}

// ---------------------------------------------------------------------------
// Fused prologue: blocks [0,128): k_prep_t transpose pass then k_score pass
// (both verbatim); blocks [128,640): k_alpha body (verbatim). One launch.
// ---------------------------------------------------------------------------
__global__ __launch_bounds__(512) void k_prep_all(
    const float* __restrict__ values, const float* __restrict__ temp,
    const float* __restrict__ ln_w, const float* __restrict__ ln_b,
    const float* __restrict__ alpha, float* __restrict__ score_ln,
    unsigned short* __restrict__ hiP, unsigned short* __restrict__ loP,
    float* __restrict__ A_soft)
{
  const int tid = threadIdx.x, w = tid >> 6, lane = tid & 63;
  if (blockIdx.x >= BB*HH){
    // ---- alpha body (verbatim k_alpha) ----
    const int row = (int)(blockIdx.x - BB*HH) * ROWS + w;
    const float SCALE = (float)(1.0/sqrt((double)FF));
    const float* ar = alpha + (size_t)row*FF + lane*8;
    float4 v0 = *(const float4*)ar;
    float4 v1 = *(const float4*)(ar+4);
    float a[8] = {v0.x*SCALE, v0.y*SCALE, v0.z*SCALE, v0.w*SCALE,
                  v1.x*SCALE, v1.y*SCALE, v1.z*SCALE, v1.w*SCALE};
    topk_softmax8(a);
    float* orow = A_soft + (size_t)row*FF + lane*8;
    *(float4*)orow     = make_float4(a[0],a[1],a[2],a[3]);
    *(float4*)(orow+4) = make_float4(a[4],a[5],a[6],a[7]);
    return;
  }
  __shared__ float tile[64][65];
  __shared__ float s_e[FF];
  __shared__ float ps[8], ps2[8];
  const int b = blockIdx.x / HH, h = blockIdx.x % HH;
  const float* vb = values + ((size_t)b*FF*HH + h)*DD;

  // ---- transpose pass (verbatim k_prep_t body, bloc_h = blockIdx.x) ----
  for (int c=0;c<8;++c){
#pragma unroll
    for (int p=0;p<8;++p){
      const int fi = p*8 + w;
      const int f  = c*64 + fi;
      tile[fi][lane] = vb[(size_t)f*HH*DD + lane];
    }
    __syncthreads();
    {
      const int d  = w*8 + (lane>>3);
      const int fj = (lane&7)*8;
      unsigned short hs[8], ls[8];
#pragma unroll
      for (int j=0;j<8;++j){
        float x = tile[fj+j][d];
        hs[j] = f2bf(x);
        ls[j] = f2bf(x - bf2f(hs[j]));
      }
      uint4 H4, L4;
      H4.x=(unsigned)hs[0]|((unsigned)hs[1]<<16); H4.y=(unsigned)hs[2]|((unsigned)hs[3]<<16);
      H4.z=(unsigned)hs[4]|((unsigned)hs[5]<<16); H4.w=(unsigned)hs[6]|((unsigned)hs[7]<<16);
      L4.x=(unsigned)ls[0]|((unsigned)ls[1]<<16); L4.y=(unsigned)ls[2]|((unsigned)ls[3]<<16);
      L4.z=(unsigned)ls[4]|((unsigned)ls[5]<<16); L4.w=(unsigned)ls[6]|((unsigned)ls[7]<<16);
      const size_t base = ((size_t)blockIdx.x*DD + d)*FF + c*64 + fj;
      *(uint4*)(hiP + base) = H4;
      *(uint4*)(loP + base) = L4;
    }
    __syncthreads();
  }

  // ---- score pass (verbatim k_score body) ----
  for (int i=0;i<FF/8;++i){
    int f = w*(FF/8) + i;
    float v = vb[(size_t)f*HH*DD + lane];
    float e = v*v;
#pragma unroll
    for (int off=32; off>=1; off>>=1) e += __shfl_xor(e, off);
    if (lane==0) s_e[f] = e * (1.0f/DD);
  }
  __syncthreads();
  float e = s_e[tid];
  float se = e, se2 = e*e;
#pragma unroll
  for (int off=32; off>=1; off>>=1){ se += __shfl_xor(se, off); se2 += __shfl_xor(se2, off); }
  if (lane==0){ ps[w]=se; ps2[w]=se2; }
  __syncthreads();
  float S1=0.f, S2=0.f;
#pragma unroll
  for (int g=0; g<8; ++g){ S1 += ps[g]; S2 += ps2[g]; }
  float meanE = S1 * (1.0f/FF);
  float rms = fmaxf(sqrtf(meanE), 1e-6f);
  float t = temp[h];
  float gain = (t > 20.f) ? t : log1pf(expf(t));
  float c = gain / rms;
  float mu = c * meanE;
  float var = c*c*(S2*(1.0f/FF) - meanE*meanE);
  float inv = rsqrtf(var + 1e-5f);
  score_ln[(size_t)blockIdx.x*FF + tid] = (c*e - mu)*inv*ln_w[tid] + ln_b[tid];
}

// Kernel 1: score_ln (FROZEN — fallback path)
__global__ __launch_bounds__(512) void k_score(const float* __restrict__ values,
    const float* __restrict__ temp, const float* __restrict__ ln_w,
    const float* __restrict__ ln_b, float* __restrict__ score_ln)
{
  const int b = blockIdx.x / HH, h = blockIdx.x % HH;
  const int tid = threadIdx.x, w = tid >> 6, lane = tid & 63;
  __shared__ float s_e[FF];
  __shared__ float ps[8], ps2[8];
  const float* vb = values + ((size_t)b*FF*HH + h)*DD;
  for (int i=0;i<FF/8;++i){
    int f = w*(FF/8) + i;
    float v = vb[(size_t)f*HH*DD + lane];
    float e = v*v;
#pragma unroll
    for (int off=32; off>=1; off>>=1) e += __shfl_xor(e, off);
    if (lane==0) s_e[f] = e * (1.0f/DD);
  }
  __syncthreads();
  float e = s_e[tid];
  float se = e, se2 = e*e;
#pragma unroll
  for (int off=32; off>=1; off>>=1){ se += __shfl_xor(se, off); se2 += __shfl_xor(se2, off); }
  if (lane==0){ ps[w]=se; ps2[w]=se2; }
  __syncthreads();
  float S1=0.f, S2=0.f;
#pragma unroll
  for (int g=0; g<8; ++g){ S1 += ps[g]; S2 += ps2[g]; }
  float meanE = S1 * (1.0f/FF);
  float rms = fmaxf(sqrtf(meanE), 1e-6f);
  float t = temp[h];
  float gain = (t > 20.f) ? t : log1pf(expf(t));
  float c = gain / rms;
  float mu = c * meanE;
  float var = c*c*(S2*(1.0f/FF) - meanE*meanE);
  float inv = rsqrtf(var + 1e-5f);
  score_ln[(size_t)blockIdx.x*FF + tid] = (c*e - mu)*inv*ln_w[tid] + ln_b[tid];
}

// Kernel 2: A_soft (FROZEN — fallback path)
__global__ __launch_bounds__(512) void k_alpha(const float* __restrict__ alpha,
                                               float* __restrict__ A_soft)
{
  const int w = threadIdx.x >> 6, lane = threadIdx.x & 63;
  const int row = blockIdx.x * ROWS + w;
  const float SCALE = (float)(1.0/sqrt((double)FF));
  const float* ar = alpha + (size_t)row*FF + lane*8;
  float4 v0 = *(const float4*)ar;
  float4 v1 = *(const float4*)(ar+4);
  float a[8] = {v0.x*SCALE, v0.y*SCALE, v0.z*SCALE, v0.w*SCALE,
                v1.x*SCALE, v1.y*SCALE, v1.z*SCALE, v1.w*SCALE};
  topk_softmax8(a);
  float* orow = A_soft + (size_t)row*FF + lane*8;
  *(float4*)orow     = make_float4(a[0],a[1],a[2],a[3]);
  *(float4*)(orow+4) = make_float4(a[4],a[5],a[6],a[7]);
}

// Kernel 2.5: transpose values -> bf16 hi/lo planes (fallback path)
__global__ __launch_bounds__(512) void k_prep_t(const float* __restrict__ values,
    unsigned short* __restrict__ hiP, unsigned short* __restrict__ loP, int b0)
{
  const int bloc_h = blockIdx.x;             // bloc*HH + h
  const int b = b0 + bloc_h / HH, h = bloc_h % HH;
  const int tid = threadIdx.x, w = tid >> 6, lane = tid & 63;
  __shared__ float tile[64][65];
  const float* vb = values + ((size_t)b*FF*HH + h)*DD;
  for (int c=0;c<8;++c){
#pragma unroll
    for (int p=0;p<8;++p){
      const int fi = p*8 + w;
      const int f  = c*64 + fi;
      tile[fi][lane] = vb[(size_t)f*HH*DD + lane];
    }
    __syncthreads();
    {
      const int d  = w*8 + (lane>>3);
      const int fj = (lane&7)*8;
      unsigned short hs[8], ls[8];
#pragma unroll
      for (int j=0;j<8;++j){
        float x = tile[fj+j][d];
        hs[j] = f2bf(x);
        ls[j] = f2bf(x - bf2f(hs[j]));
      }
      uint4 H4, L4;
      H4.x=(unsigned)hs[0]|((unsigned)hs[1]<<16); H4.y=(unsigned)hs[2]|((unsigned)hs[3]<<16);
      H4.z=(unsigned)hs[4]|((unsigned)hs[5]<<16); H4.w=(unsigned)hs[6]|((unsigned)hs[7]<<16);
      L4.x=(unsigned)ls[0]|((unsigned)ls[1]<<16); L4.y=(unsigned)ls[2]|((unsigned)ls[3]<<16);
      L4.z=(unsigned)ls[4]|((unsigned)ls[5]<<16); L4.w=(unsigned)ls[6]|((unsigned)ls[7]<<16);
      const size_t base = ((size_t)bloc_h*DD + d)*FF + c*64 + fj;
      *(uint4*)(hiP + base) = H4;
      *(uint4*)(loP + base) = L4;
    }
    __syncthreads();
  }
}

// ---------- phase-1 helper (FROZEN — validated bits) ----------
__device__ __forceinline__ void build_mix_row(int bh, int h, int s, int lane,
    const float* __restrict__ score_ln, const float* __restrict__ gamma,
    const float* __restrict__ U, const float* __restrict__ V,
    const float* __restrict__ A_soft, float4& m0, float4& m1)
{
  const int f0 = lane*8;
  const float* sr = score_ln + (size_t)bh*FF + f0;
  float4 sv0 = *(const float4*)sr;
  float4 sv1 = *(const float4*)(sr+4);
  const float g = gamma[h*SS + s];
  float dl[8] = {sv0.x+g, sv0.y+g, sv0.z+g, sv0.w+g,
                 sv1.x+g, sv1.y+g, sv1.z+g, sv1.w+g};
  const float* Ur = U + ((size_t)h*SS + s)*RANKK;
  const float* Vh = V + (size_t)h*RANKK*FF + f0;
#pragma unroll
  for (int r=0;r<RANKK;++r){
    float u = Ur[r];
    float4 b0 = *(const float4*)(Vh + r*FF);
    float4 b1 = *(const float4*)(Vh + r*FF + 4);
    dl[0] += u*b0.x; dl[1] += u*b0.y; dl[2] += u*b0.z; dl[3] += u*b0.w;
    dl[4] += u*b1.x; dl[5] += u*b1.y; dl[6] += u*b1.z; dl[7] += u*b1.w;
  }
  topk_softmax8(dl);
  const float* arow = A_soft + ((size_t)h*SS + s)*FF + f0;
  float4 a0 = *(const float4*)arow;
  float4 a1 = *(const float4*)(arow+4);
  m0 = make_float4(dl[0]+a0.x, dl[1]+a0.y, dl[2]+a0.z, dl[3]+a0.w);
  m1 = make_float4(dl[4]+a1.x, dl[5]+a1.y, dl[6]+a1.z, dl[7]+a1.w);
}

__device__ __forceinline__ void gload16(const void* g, void* l){
  __builtin_amdgcn_global_load_lds(
      (const __attribute__((address_space(1))) unsigned int*)g,
      (__attribute__((address_space(3))) unsigned int*)l, 16, 0, 0);
}

// ---------- MFMA main: 32 s-rows x 64 d per block; B async-staged in LDS ----
// 1-barrier K-loop: per iter {vmcnt(0)+lgkm(0); barrier; issue stage(t+1);
// ds_read; MFMA(setprio 1)}. vmcnt0+barrier => all waves' stage(t) landed;
// lgkm0+barrier => all t-1 reads retired before stage overwrites that buffer.
template<int NB>
__global__ __launch_bounds__(512, 4) void k_mfma_t(
    const unsigned short* __restrict__ hiP, const unsigned short* __restrict__ loP,
    const float* __restrict__ gamma, const float* __restrict__ U,
    const float* __restrict__ V, const float* __restrict__ score_ln,
    const float* __restrict__ A_soft, float* __restrict__ out, int b0)
{
  __shared__ __align__(16) unsigned char Abuf[65536];   // A hi [0,32K), lo [32K,64K)
  __shared__ __align__(16) unsigned char Bbuf[2][8192]; // B chunk dbuf
  const int nwg = HH*NB*16;
  const int bid = (blockIdx.x & 7)*(nwg/8) + (blockIdx.x >> 3); // XCD chunk swizzle
  const int grp  = bid >> 4;           // h*NB + bloc
  const int sblk = bid & 15;
  const int h    = grp / NB;
  const int bloc = grp % NB;
  const int b    = b0 + bloc;
  const int s0   = sblk*32;
  const int bh   = b*HH + h;
  const int tid = threadIdx.x, w = tid>>6, lane = tid&63;

  // ---- staging source decode (rule 21: linear LDS dest, pre-swizzled src) ----
  const size_t pbBase = (size_t)(bloc*HH + h)*DD*FF;
  const int dw  = tid >> 3;            // d row 0..63
  const int s8p = tid & 7;             // swizzled 16B slot in 128B row
  const int s8  = s8p ^ (dw & 7);      // unswizzled slot: plane*4 + seg
  const unsigned short* sp = ((s8 & 4) ? loP : hiP)
                             + pbBase + (size_t)dw*FF + (size_t)(s8 & 3)*8;
  // stage(0) NOW — latency hides under phase-1 top-k
  gload16(sp, &Bbuf[0][(unsigned)w<<10]);

  // ---- phase 1: wave w builds mix rows sl = w*4 .. w*4+3, stage bf16 hi/lo ----
#pragma unroll
  for (int i=0;i<4;++i){
    const int sl = w*4 + i;
    float4 m0, m1;
    build_mix_row(bh, h, s0+sl, lane, score_ln, gamma, U, V, A_soft, m0, m1);
    float xs[8] = {m0.x,m0.y,m0.z,m0.w,m1.x,m1.y,m1.z,m1.w};
    unsigned short hs[8], ls[8];
#pragma unroll
    for (int j=0;j<8;++j){
      hs[j] = f2bf(xs[j]);
      ls[j] = f2bf(xs[j] - bf2f(hs[j]));
    }
    uint4 H4, L4;
    H4.x = (unsigned)hs[0] | ((unsigned)hs[1]<<16);
    H4.y = (unsigned)hs[2] | ((unsigned)hs[3]<<16);
    H4.z = (unsigned)hs[4] | ((unsigned)hs[5]<<16);
    H4.w = (unsigned)hs[6] | ((unsigned)hs[7]<<16);
    L4.x = (unsigned)ls[0] | ((unsigned)ls[1]<<16);
    L4.y = (unsigned)ls[2] | ((unsigned)ls[3]<<16);
    L4.z = (unsigned)ls[4] | ((unsigned)ls[5]<<16);
    L4.w = (unsigned)ls[6] | ((unsigned)ls[7]<<16);
    const unsigned byt = (unsigned)(sl*1024 + lane*16) ^ (unsigned)((sl&15)<<4);
    *(uint4*)(Abuf + byt)          = H4;
    *(uint4*)(Abuf + 32768 + byt)  = L4;
  }
  __syncthreads();   // drains everything incl. stage(0)

  // ---- phase 2: wave (stile,ntile) computes 16s x 16d, K=512 ----
  const int stile = w>>2, ntile = w&3;
  const int srow  = stile*16 + (lane&15);
  const unsigned sw = (unsigned)((lane&15)<<4);
  const unsigned a0off = (unsigned)(srow*1024 + ((lane>>4)*16));
  const int d    = ntile*16 + (lane&15);
  const int sgr  = lane>>4;
  const unsigned offH = (unsigned)(d*128 + ((sgr    ) ^ (d&7))*16);
  const unsigned offL = (unsigned)(d*128 + ((sgr + 4) ^ (d&7))*16);

  f32x4 acc0 = {0.f,0.f,0.f,0.f};
  f32x4 acc1 = {0.f,0.f,0.f,0.f};

#pragma unroll
  for (int t=0;t<16;++t){
    if (t > 0){
      asm volatile("s_waitcnt vmcnt(0) lgkmcnt(0)" ::: "memory");
      __builtin_amdgcn_s_barrier();
    }
    if (t < 15)
      gload16(sp + (size_t)(t+1)*32, &Bbuf[(t+1)&1][(unsigned)w<<10]);
    const unsigned ax = (a0off + (unsigned)(t*64)) ^ sw;
    bf16x8 ah = *(const bf16x8*)(Abuf + ax);
    bf16x8 al = *(const bf16x8*)(Abuf + 32768 + ax);
    const unsigned char* bb = Bbuf[t&1];
    bf16x8 bhv = *(const bf16x8*)(bb + offH);
    bf16x8 blv = *(const bf16x8*)(bb + offL);
    __builtin_amdgcn_s_setprio(1);
    acc0 = __builtin_amdgcn_mfma_f32_16x16x32_bf16(ah, bhv, acc0, 0, 0, 0);
    acc1 = __builtin_amdgcn_mfma_f32_16x16x32_bf16(al, bhv, acc1, 0, 0, 0);
    acc1 = __builtin_amdgcn_mfma_f32_16x16x32_bf16(ah, blv, acc1, 0, 0, 0);
    __builtin_amdgcn_s_setprio(0);
  }

  // ---- epilogue: C/D map col=lane&15 (n=d), row=(lane>>4)*4+reg (m=s) ----
  const int m0r = stile*16 + (lane>>4)*4;
#pragma unroll
  for (int r=0;r<4;++r){
    const int s = s0 + m0r + r;
    __builtin_nontemporal_store(acc0[r] + acc1[r],
        &out[(((size_t)b*SS + s)*HH + h)*DD + d]);
  }
}

// ---------- fallback: r1 LDS-broadcast kernel (tiny-ws safety) ----------
__global__ __launch_bounds__(512) void k_main_lds(const float* __restrict__ values,
    const float* __restrict__ alpha, const float* __restrict__ gamma,
    const float* __restrict__ U, const float* __restrict__ V,
    const float* __restrict__ score_ln, float* __restrict__ out)
{
  const int nwg = BB*HH*(SS/ROWS);
  const int bid = (blockIdx.x & 7)*(nwg/8) + (blockIdx.x >> 3);
  const int blocksPerBH = SS / ROWS;
  const int bh = bid / blocksPerBH;
  const int s0 = (bid % blocksPerBH) * ROWS;
  const int b = bh / HH, h = bh % HH;
  const int tid = threadIdx.x, w = tid >> 6, lane = tid & 63;
  __shared__ float smix[ROWS][FF];

  {
    const int s = s0 + w;
    const int f0 = lane*8;
    const float* sr = score_ln + (size_t)bh*FF + f0;
    float4 sv0 = *(const float4*)sr;
    float4 sv1 = *(const float4*)(sr+4);
    const float g = gamma[h*SS + s];
    float dl[8] = {sv0.x+g, sv0.y+g, sv0.z+g, sv0.w+g,
                   sv1.x+g, sv1.y+g, sv1.z+g, sv1.w+g};
    const float* Ur = U + ((size_t)h*SS + s)*RANKK;
    const float* Vh = V + (size_t)h*RANKK*FF + f0;
#pragma unroll
    for (int r=0;r<RANKK;++r){
      float u = Ur[r];
      float4 b0 = *(const float4*)(Vh + r*FF);
      float4 b1 = *(const float4*)(Vh + r*FF + 4);
      dl[0] += u*b0.x; dl[1] += u*b0.y; dl[2] += u*b0.z; dl[3] += u*b0.w;
      dl[4] += u*b1.x; dl[5] += u*b1.y; dl[6] += u*b1.z; dl[7] += u*b1.w;
    }
    topk_softmax8(dl);
    const float SCALE = (float)(1.0/sqrt((double)FF));
    const float* arow = alpha + ((size_t)h*SS + s)*FF + f0;
    float4 a0 = *(const float4*)arow;
    float4 a1 = *(const float4*)(arow+4);
    float ap[8] = {a0.x*SCALE, a0.y*SCALE, a0.z*SCALE, a0.w*SCALE,
                   a1.x*SCALE, a1.y*SCALE, a1.z*SCALE, a1.w*SCALE};
    topk_softmax8(ap);
    float4 m0 = make_float4(dl[0]+ap[0], dl[1]+ap[1], dl[2]+ap[2], dl[3]+ap[3]);
    float4 m1 = make_float4(dl[4]+ap[4], dl[5]+ap[5], dl[6]+ap[6], dl[7]+ap[7]);
    *(float4*)&smix[w][f0]   = m0;
    *(float4*)&smix[w][f0+4] = m1;
  }
  __syncthreads();

  float acc[ROWS] = {0,0,0,0,0,0,0,0};
  {
    const float* vp = values + (size_t)b*FF*HH*DD + (size_t)h*DD + lane;
#pragma unroll
    for (int i=0;i<16;++i){
      const int f0 = w*64 + i*4;
      float x0 = vp[(size_t)(f0+0)*HH*DD];
      float x1 = vp[(size_t)(f0+1)*HH*DD];
      float x2 = vp[(size_t)(f0+2)*HH*DD];
      float x3 = vp[(size_t)(f0+3)*HH*DD];
#pragma unroll
      for (int r=0;r<ROWS;++r){
        float4 m = *(const float4*)&smix[r][f0];
        acc[r] += m.x*x0 + m.y*x1 + m.z*x2 + m.w*x3;
      }
    }
  }
  __syncthreads();

  float* red = &smix[0][0];
#pragma unroll
  for (int r=0;r<ROWS;++r) red[(w*ROWS + r)*64 + lane] = acc[r];
  __syncthreads();
  {
    const int r = w, dd = lane;
    float sum = 0.f;
#pragma unroll
    for (int g=0; g<8; ++g) sum += red[(g*ROWS + r)*64 + dd];
    out[(((size_t)b*SS + s0 + r)*HH + h)*DD + dd] = sum;
  }
}

extern "C" void kernel_launch(void* const* d_in, const int* in_sizes, int n_in,
                              void* d_out, int out_size, void* d_ws, size_t ws_size,
                              hipStream_t stream) {
  const float* values = (const float*)d_in[0];
  const float* alpha  = (const float*)d_in[1];
  const float* temp   = (const float*)d_in[2];
  const float* gamma  = (const float*)d_in[3];
  const float* U      = (const float*)d_in[4];
  const float* V      = (const float*)d_in[5];
  const float* ln_w   = (const float*)d_in[6];
  const float* ln_b   = (const float*)d_in[7];
  float* out = (float*)d_out;
  float* ws  = (float*)d_ws;

  const size_t scoreN = (size_t)BB*HH*FF;             // 65,536 floats
  const size_t alphaN = (size_t)HH*SS*FF;             // 2,097,152 floats
  const size_t planeFull = (size_t)BB*HH*DD*FF;       // 4,194,304 ushorts/plane
  const size_t planeHalf = planeFull/2;

  float* score_ln = ws;
  float* A_soft   = ws + scoreN;
  unsigned short* hiP = (unsigned short*)(ws + scoreN + alphaN);

  const size_t baseB    = (scoreN + alphaN)*sizeof(float);             // 8.65 MB
  const size_t needFull = baseB + 2*planeFull*sizeof(unsigned short);  // 25.4 MB
  const size_t needHalf = baseB + 2*planeHalf*sizeof(unsigned short);  // 17.0 MB (r2-proven)

  if (ws_size >= needFull){
    unsigned short* loP = hiP + planeFull;
    hipLaunchKernelGGL(k_prep_all, dim3(BB*HH + HH*SS/ROWS), dim3(512), 0, stream,
                       values, temp, ln_w, ln_b, alpha, score_ln, hiP, loP, A_soft);
    hipLaunchKernelGGL((k_mfma_t<BB>), dim3(HH*16*BB), dim3(512), 0, stream,
                       hiP, loP, gamma, U, V, score_ln, A_soft, out, 0);
  } else if (ws_size >= needHalf){
    unsigned short* loP = hiP + planeHalf;
    hipLaunchKernelGGL(k_score, dim3(BB*HH), dim3(512), 0, stream,
                       values, temp, ln_w, ln_b, score_ln);
    hipLaunchKernelGGL(k_alpha, dim3(HH*SS/ROWS), dim3(512), 0, stream, alpha, A_soft);
    for (int c=0;c<2;++c){
      hipLaunchKernelGGL(k_prep_t, dim3((BB/2)*HH), dim3(512), 0, stream,
                         values, hiP, loP, c*(BB/2));
      hipLaunchKernelGGL((k_mfma_t<BB/2>), dim3(HH*16*(BB/2)), dim3(512), 0, stream,
                         hiP, loP, gamma, U, V, score_ln, A_soft, out, c*(BB/2));
    }
  } else {
    hipLaunchKernelGGL(k_score, dim3(BB*HH), dim3(512), 0, stream,
                       values, temp, ln_w, ln_b, score_ln);
    hipLaunchKernelGGL(k_main_lds, dim3(BB*HH*(SS/ROWS)), dim3(512), 0, stream,
                       values, alpha, gamma, U, V, score_ln, out);
  }
}